// Round 13
// baseline (197.045 us; speedup 1.0000x reference)
//
#include <hip/hip_runtime.h>

typedef __attribute__((ext_vector_type(4))) float f32x4;
typedef __attribute__((ext_vector_type(8))) short s16x8;
typedef __attribute__((ext_vector_type(4))) short s16x4;
typedef __bf16 bf16x4 __attribute__((ext_vector_type(4)));

#define B_   96
#define NQ   35
#define LP   180
#define H_   768
#define D_   128
#define NEGF (-1e30f)

#define NROWS 37920
#define QROWS 3360
#define PROWS 17280

__device__ __forceinline__ unsigned short f2bf(float f) {
    return __builtin_bit_cast(unsigned short, (__bf16)f);
}

__device__ __forceinline__ s16x8 pack_bf16(f32x4 v0, f32x4 v1) {
    bf16x4 h0 = __builtin_convertvector(v0, bf16x4);
    bf16x4 h1 = __builtin_convertvector(v1, bf16x4);
    s16x4 a = __builtin_bit_cast(s16x4, h0), b = __builtin_bit_cast(s16x4, h1);
    return __builtin_shufflevector(a, b, 0, 1, 2, 3, 4, 5, 6, 7);
}

// async global->LDS, 16 B per lane; lds dest must be wave-uniform (HW adds lane*16)
__device__ __forceinline__ void glds16(const void* g, void* l) {
    __builtin_amdgcn_global_load_lds(
        (const __attribute__((address_space(1))) unsigned int*)g,
        (__attribute__((address_space(3))) unsigned int*)l,
        16, 0, 0);
}

// ---------------- prep: wt_build (blocks 0-47) + mask canon w/ local detect (48-182) ----
__global__ __launch_bounds__(256) void prep_k(
    const float* __restrict__ W, unsigned short* __restrict__ wthi,
    const void* __restrict__ pm, const void* __restrict__ nm,
    unsigned char* __restrict__ maskc) {
    __shared__ unsigned int rr[256];
    int b = blockIdx.x, t = threadIdx.x;
    if (b < 48) {
        int tid = b * 256 + t;
        int nt = tid / (24 * 64);
        int r = tid - nt * 24 * 64;
        int ks = r / 64, lane = r - ks * 64;
        int m = lane & 15, quad = lane >> 4;
        unsigned short* o = wthi + (size_t)tid * 8;
#pragma unroll
        for (int j = 0; j < 8; j++) {
            int k = ks * 32 + quad * 8 + j;
            o[j] = f2bf(W[(size_t)k * D_ + nt * 16 + m]);
        }
    } else {
        const unsigned int* pw = (const unsigned int*)pm;
        unsigned int f1 = 0, f3 = 0, f4 = 0;
        for (int w = t; w < 4320; w += 256) {
            unsigned int v = pw[w];
            f1 |= v & 0x0000ff00u;                 // byte %4==1 -> 1-byte layout
            f3 |= v & 0xff000000u;                 // byte %4==3 -> float32
            if (w & 1) f4 |= v & 0x000000ffu;      // byte %8==4 -> int32
        }
        rr[t] = f1; __syncthreads();
        for (int s2 = 128; s2; s2 >>= 1) { if (t < s2) rr[t] |= rr[t + s2]; __syncthreads(); }
        unsigned int c1 = rr[0]; __syncthreads();
        rr[t] = f3; __syncthreads();
        for (int s2 = 128; s2; s2 >>= 1) { if (t < s2) rr[t] |= rr[t + s2]; __syncthreads(); }
        unsigned int c3 = rr[0]; __syncthreads();
        rr[t] = f4; __syncthreads();
        for (int s2 = 128; s2; s2 >>= 1) { if (t < s2) rr[t] |= rr[t + s2]; __syncthreads(); }
        unsigned int c4 = rr[0];
        int i = (b - 48) * 256 + t;                // < 34560 exactly (135 blocks)
        const void* src = (i < B_ * LP) ? pm : nm;
        int j = (i < B_ * LP) ? i : i - B_ * LP;
        bool bit;
        if (c1 > 0)       bit = ((const unsigned char*)src)[j] != 0;
        else if (c3 > 0)  bit = ((const float*)src)[j] != 0.0f;
        else if (c4 > 0)  bit = ((const int*)src)[j] != 0;
        else              bit = ((const long long*)src)[j] != 0;
        maskc[i] = bit ? 1 : 0;
    }
}

// ---------------- proj v10: passage-fused proj+normalize+scatter (unchanged from R8) ----
__global__ __launch_bounds__(512, 1) void proj_k(
    const float* __restrict__ qh, const float* __restrict__ ph, const float* __restrict__ nh,
    const unsigned short* __restrict__ wthi, const float* __restrict__ bias,
    const unsigned char* __restrict__ maskc,
    unsigned short* __restrict__ qfrag, unsigned short* __restrict__ pfrag) {
    __shared__ float sb[24576];                      // 96 KB: 2 x 192 x 64 f32 staging
    int b = blockIdx.x, t = threadIdx.x;
    int wave = t >> 6, lane = t & 63;
    int m = lane & 15, quad = lane >> 4;
    unsigned short* xb = (unsigned short*)sb;        // post-loop transpose buffer

    if (b < 192) {
        const float* src = (b < 96) ? ph + (size_t)b * LP * H_
                                    : nh + (size_t)(b - 96) * LP * H_;
        const float* gp[6];
#pragma unroll
        for (int g = 0; g < 6; g++) {
            int rl = wave * 24 + g * 4 + (lane >> 4);
            int rc = rl < LP ? rl : LP - 1;
            gp[g] = src + (size_t)rc * H_ + (((lane & 15) ^ (2 * (rl & 7))) << 2);
        }

        f32x4 acc[12];
#pragma unroll
        for (int mt = 0; mt < 12; mt++) acc[mt] = (f32x4){0.f, 0.f, 0.f, 0.f};

        {
            float* d0 = sb + wave * 1536;
#pragma unroll
            for (int g = 0; g < 6; g++) glds16(gp[g], d0 + g * 256);
        }
        __syncthreads();

        for (int s = 0; s < 12; s++) {
            if (s < 11) {
                float* d0 = sb + ((s + 1) & 1) * 12288 + wave * 1536;
#pragma unroll
                for (int g = 0; g < 6; g++) glds16(gp[g] + (s + 1) * 64, d0 + g * 256);
            }
            const float* bb = sb + (s & 1) * 12288;
#pragma unroll
            for (int ksg = 0; ksg < 2; ksg++) {
                s16x8 bf = *(const s16x8*)(wthi +
                           ((size_t)(wave * 24 + s * 2 + ksg) * 64 + lane) * 8);
                int kc = ksg * 8 + quad * 2;
#pragma unroll
                for (int mt = 0; mt < 12; mt++) {
                    int row = mt * 16 + m;
                    const float* fb = bb + row * 64 + ((kc ^ (2 * (row & 7))) << 2);
                    f32x4 lo = *(const f32x4*)fb, hi = *(const f32x4*)(fb + 4);
                    acc[mt] = __builtin_amdgcn_mfma_f32_16x16x32_bf16(
                        pack_bf16(lo, hi), bf, acc[mt], 0, 0, 0);
                }
            }
            __syncthreads();
        }

        float bv = bias[wave * 16 + m];
        float s2 = 0.f;
#pragma unroll
        for (int mt = 0; mt < 12; mt++)
#pragma unroll
            for (int r = 0; r < 4; r++) {
                int prow = mt * 16 + quad * 4 + r;
                float v = acc[mt][r] + bv;
                acc[mt][r] = v;
                if (prow < LP) s2 += v * v;
            }
        s2 += __shfl_xor(s2, 16); s2 += __shfl_xor(s2, 32);
        float sc = rsqrtf(fmaxf(s2, 1e-24f));
        __syncthreads();
#pragma unroll
        for (int mt = 0; mt < 12; mt++)
#pragma unroll
            for (int r = 0; r < 4; r++) {
                int prow = mt * 16 + quad * 4 + r;
                if (prow < LP) xb[prow * 136 + wave * 16 + m] = f2bf(acc[mt][r] * sc);
            }
        __syncthreads();
        const unsigned char* mk = maskc + b * LP;
        unsigned short* pdst = pfrag + (size_t)b * 24576;
#pragma unroll
        for (int i = 0; i < 6; i++) {
            int ch = t + i * 512;
            int ln = ch & 63;
            int l = ((ch >> 8) << 4) + (ln & 15);
            int lsrc = (l < LP && mk[l]) ? l : 0;
            int d0 = ((ch >> 6) & 3) * 32 + (ln >> 4) * 8;
            *(s16x8*)&pdst[(size_t)ch * 8] = *(const s16x8*)&xb[lsrc * 136 + d0];
        }
    } else {
        int qp = b - 192;                            // [0,48)
        const float* src = qh + (size_t)qp * 70 * H_;
        const float* gp[3];
#pragma unroll
        for (int g = 0; g < 3; g++) {
            int rl = wave * 12 + g * 4 + (lane >> 4);
            int rc = rl < 70 ? rl : 69;
            gp[g] = src + (size_t)rc * H_ + (((lane & 15) ^ (2 * (rl & 7))) << 2);
        }

        f32x4 acc[5];
#pragma unroll
        for (int mt = 0; mt < 5; mt++) acc[mt] = (f32x4){0.f, 0.f, 0.f, 0.f};

        {
            float* d0 = sb + wave * 768;
#pragma unroll
            for (int g = 0; g < 3; g++) glds16(gp[g], d0 + g * 256);
        }
        __syncthreads();

        for (int s = 0; s < 12; s++) {
            if (s < 11) {
                float* d0 = sb + ((s + 1) & 1) * 6144 + wave * 768;
#pragma unroll
                for (int g = 0; g < 3; g++) glds16(gp[g] + (s + 1) * 64, d0 + g * 256);
            }
            const float* bb = sb + (s & 1) * 6144;
#pragma unroll
            for (int ksg = 0; ksg < 2; ksg++) {
                s16x8 bf = *(const s16x8*)(wthi +
                           ((size_t)(wave * 24 + s * 2 + ksg) * 64 + lane) * 8);
                int kc = ksg * 8 + quad * 2;
#pragma unroll
                for (int mt = 0; mt < 5; mt++) {
                    int row = mt * 16 + m;
                    const float* fb = bb + row * 64 + ((kc ^ (2 * (row & 7))) << 2);
                    f32x4 lo = *(const f32x4*)fb, hi = *(const f32x4*)(fb + 4);
                    acc[mt] = __builtin_amdgcn_mfma_f32_16x16x32_bf16(
                        pack_bf16(lo, hi), bf, acc[mt], 0, 0, 0);
                }
            }
            __syncthreads();
        }

        float bv = bias[wave * 16 + m];
        float s0 = 0.f, s1 = 0.f;
#pragma unroll
        for (int mt = 0; mt < 5; mt++)
#pragma unroll
            for (int r = 0; r < 4; r++) {
                int prow = mt * 16 + quad * 4 + r;
                float v = acc[mt][r] + bv;
                acc[mt][r] = v;
                if (prow < 35) s0 += v * v;
                else if (prow < 70) s1 += v * v;
            }
        s0 += __shfl_xor(s0, 16); s0 += __shfl_xor(s0, 32);
        s1 += __shfl_xor(s1, 16); s1 += __shfl_xor(s1, 32);
        float sc0 = rsqrtf(fmaxf(s0, 1e-24f));
        float sc1 = rsqrtf(fmaxf(s1, 1e-24f));
        __syncthreads();
#pragma unroll
        for (int mt = 0; mt < 5; mt++)
#pragma unroll
            for (int r = 0; r < 4; r++) {
                int prow = mt * 16 + quad * 4 + r;
                if (prow < 70)
                    xb[prow * 136 + wave * 16 + m] =
                        f2bf(acc[mt][r] * (prow < 35 ? sc0 : sc1));
            }
        __syncthreads();
        unsigned short* qdst = qfrag + (size_t)qp * 10240;
#pragma unroll
        for (int i = 0; i < 3; i++) {
            int ch = t + i * 512;
            if (ch < 1280) {
                int ln = ch & 63;
                int prow = ((ch >> 8) << 4) + (ln & 15);
                int d0 = ((ch >> 6) & 3) * 32 + (ln >> 4) * 8;
                s16x8 v = (s16x8){0, 0, 0, 0, 0, 0, 0, 0};
                if (prow < 70) v = *(const s16x8*)&xb[prow * 136 + d0];
                *(s16x8*)&qdst[(size_t)ch * 8] = v;
            }
        }
    }
}

// ---------------- interact v6: single-pass, 2304 blocks, wave-split halves --------------
// R12 accounting: v5 ~= 35-37 us vs ~18-20 floor; the slack is the 3 SERIAL passes per
// block (two barriers each, q reloaded per pass) on a 768-block grid (3/CU). v6 removes
// the pass loop: one block per (c, qg) -- the R0-proven 2304-block coverage -- with
// v5's verified wave-split halves (waves 0-3: mts 0-2, waves 4-7: mts 3-4; live sets
// ~95/~75 VGPR, spill-free by construction). Each block: stage p once (48 KB, 3
// blocks/CU resident, 9 queued -> deep tail overlap), ONE nt-sweep per wave, one
// barrier, combine, exit. Extra p-staging (2304 x 48 KB = 110 MB) is L2-hot (pfrag
// 9.4 MB, XCD-pinned) ~3 us aggregate. MFMA core / fragments / reductions unchanged.
__global__ __launch_bounds__(512, 1) void interact_k(
    const unsigned short* __restrict__ qfrag, const unsigned short* __restrict__ pfrag,
    float* __restrict__ out) {
    __shared__ unsigned short plds[24576];           // 48 KB p-tile, shared by all 8 waves
    __shared__ float comb[4][2];                     // half-B partials per wq
    int wave = threadIdx.x >> 6, lane = threadIdx.x & 63;
    int b = blockIdx.x;                              // 2304 blocks
    int xcd = b & 7, i = b >> 3;                     // i in [0,288)
    int c = xcd * 24 + (i % 24);                     // [0,192)
    int qg = i / 24;                                 // [0,12)
    int side = c / 96, pb = c - side * 96;
    int wq = wave & 3, half = wave >> 2;
    int qp = qg * 4 + wq;                            // [0,48)
    int m = lane & 15, quad = lane >> 4;

    const unsigned short* pbase = pfrag + (size_t)c * 24576;
    const unsigned short* qbase = qfrag + (size_t)qp * 10240;

    // stage p-tile: waves 0-3 take nt {w, w+8}; waves 4-7 take nt {w}
#pragma unroll
    for (int g = 0; g < 2; g++) {
        int nt = wave + g * 8;
        if (nt < 12) {
#pragma unroll
            for (int ks = 0; ks < 4; ks++)
                glds16(pbase + ((size_t)(nt * 4 + ks) * 64 + lane) * 8,
                       &plds[(size_t)(nt * 4 + ks) * 512]);
        }
    }
    __syncthreads();                                 // drain staging; plds read-only after

    const f32x4 zero4 = (f32x4){0.f, 0.f, 0.f, 0.f};
    float s0 = 0.f, s1 = 0.f;

    if (half == 0) {
        // ---------- waves 0-3: mts 0..2 (live ~95 VGPR) ----------
        s16x8 a[3][4];
#pragma unroll
        for (int mt = 0; mt < 3; mt++)
#pragma unroll
            for (int ks = 0; ks < 4; ks++)
                a[mt][ks] = *(const s16x8*)(qbase +
                            ((size_t)(mt * 4 + ks) * 64 + lane) * 8);
        float rmax[3][4];
#pragma unroll
        for (int mt = 0; mt < 3; mt++)
#pragma unroll
            for (int rr = 0; rr < 4; rr++) rmax[mt][rr] = NEGF;

        for (int nt = 0; nt < 12; nt++) {
            s16x8 bfr[4];
#pragma unroll
            for (int ks = 0; ks < 4; ks++)
                bfr[ks] = *(const s16x8*)&plds[((size_t)(nt * 4 + ks) * 64 + lane) * 8];
            __builtin_amdgcn_s_setprio(1);
#pragma unroll
            for (int mt = 0; mt < 3; mt++) {
                f32x4 acc = __builtin_amdgcn_mfma_f32_16x16x32_bf16(a[mt][0], bfr[0], zero4, 0, 0, 0);
                acc = __builtin_amdgcn_mfma_f32_16x16x32_bf16(a[mt][1], bfr[1], acc, 0, 0, 0);
                acc = __builtin_amdgcn_mfma_f32_16x16x32_bf16(a[mt][2], bfr[2], acc, 0, 0, 0);
                acc = __builtin_amdgcn_mfma_f32_16x16x32_bf16(a[mt][3], bfr[3], acc, 0, 0, 0);
#pragma unroll
                for (int rr = 0; rr < 4; rr++)
                    rmax[mt][rr] = fmaxf(rmax[mt][rr], acc[rr]);
            }
            __builtin_amdgcn_s_setprio(0);
        }
#pragma unroll
        for (int mt = 0; mt < 3; mt++)
#pragma unroll
            for (int rr = 0; rr < 4; rr++) {
                float v = rmax[mt][rr];
                v = fmaxf(v, __shfl_xor(v, 1));
                v = fmaxf(v, __shfl_xor(v, 2));
                v = fmaxf(v, __shfl_xor(v, 4));
                v = fmaxf(v, __shfl_xor(v, 8));
                int prow = mt * 16 + quad * 4 + rr;
                if (prow < 35) s0 += v;
                else if (prow < 70) s1 += v;
            }
    } else {
        // ---------- waves 4-7: mts 3..4 (live ~75 VGPR) ----------
        s16x8 a[2][4];
#pragma unroll
        for (int mt = 0; mt < 2; mt++)
#pragma unroll
            for (int ks = 0; ks < 4; ks++)
                a[mt][ks] = *(const s16x8*)(qbase +
                            ((size_t)((mt + 3) * 4 + ks) * 64 + lane) * 8);
        float rmax[2][4];
#pragma unroll
        for (int mt = 0; mt < 2; mt++)
#pragma unroll
            for (int rr = 0; rr < 4; rr++) rmax[mt][rr] = NEGF;

        for (int nt = 0; nt < 12; nt++) {
            s16x8 bfr[4];
#pragma unroll
            for (int ks = 0; ks < 4; ks++)
                bfr[ks] = *(const s16x8*)&plds[((size_t)(nt * 4 + ks) * 64 + lane) * 8];
            __builtin_amdgcn_s_setprio(1);
#pragma unroll
            for (int mt = 0; mt < 2; mt++) {
                f32x4 acc = __builtin_amdgcn_mfma_f32_16x16x32_bf16(a[mt][0], bfr[0], zero4, 0, 0, 0);
                acc = __builtin_amdgcn_mfma_f32_16x16x32_bf16(a[mt][1], bfr[1], acc, 0, 0, 0);
                acc = __builtin_amdgcn_mfma_f32_16x16x32_bf16(a[mt][2], bfr[2], acc, 0, 0, 0);
                acc = __builtin_amdgcn_mfma_f32_16x16x32_bf16(a[mt][3], bfr[3], acc, 0, 0, 0);
#pragma unroll
                for (int rr = 0; rr < 4; rr++)
                    rmax[mt][rr] = fmaxf(rmax[mt][rr], acc[rr]);
            }
            __builtin_amdgcn_s_setprio(0);
        }
#pragma unroll
        for (int mt = 0; mt < 2; mt++)
#pragma unroll
            for (int rr = 0; rr < 4; rr++) {
                float v = rmax[mt][rr];
                v = fmaxf(v, __shfl_xor(v, 1));
                v = fmaxf(v, __shfl_xor(v, 2));
                v = fmaxf(v, __shfl_xor(v, 4));
                v = fmaxf(v, __shfl_xor(v, 8));
                int prow = (mt + 3) * 16 + quad * 4 + rr;
                if (prow < 35) s0 += v;
                else if (prow < 70) s1 += v;
            }
    }

    s0 += __shfl_xor(s0, 16); s0 += __shfl_xor(s0, 32);
    s1 += __shfl_xor(s1, 16); s1 += __shfl_xor(s1, 32);
    if (half == 1 && lane == 0) { comb[wq][0] = s0; comb[wq][1] = s1; }
    __syncthreads();                                 // half-B partials visible
    if (half == 0 && lane == 0) {
        int qb0 = qp * 2, qb1 = qp * 2 + 1;
        out[(size_t)qb0 * (2 * B_) + side * B_ + pb] = s0 + comb[wq][0];
        out[(size_t)qb1 * (2 * B_) + side * B_ + pb] = s1 + comb[wq][1];
    }
}

// ---------------- launch ----------------
extern "C" void kernel_launch(void* const* d_in, const int* in_sizes, int n_in,
                              void* d_out, int out_size, void* d_ws, size_t ws_size,
                              hipStream_t stream) {
    const float* qh   = (const float*)d_in[0];
    const float* ph   = (const float*)d_in[1];
    const float* nh   = (const float*)d_in[2];
    const float* W    = (const float*)d_in[3];
    const float* bias = (const float*)d_in[4];
    const void* pmask = d_in[5];
    const void* nmask = d_in[6];
    float* out = (float*)d_out;
    char* ws = (char*)d_ws;

    constexpr size_t WTHI_OFF  = 256;                        // 196608 B
    constexpr size_t MASKC_OFF = WTHI_OFF + 196608;          // 34560 B
    constexpr size_t QFRAG_OFF = MASKC_OFF + 34560;          // 983040 B
    constexpr size_t PFRAG_OFF = QFRAG_OFF + 983040;         // 9437184 B

    unsigned short* wthi   = (unsigned short*)(ws + WTHI_OFF);
    unsigned char* maskc   = (unsigned char*)(ws + MASKC_OFF);
    unsigned short* qfrag  = (unsigned short*)(ws + QFRAG_OFF);
    unsigned short* pfrag  = (unsigned short*)(ws + PFRAG_OFF);

    prep_k<<<183, 256, 0, stream>>>(W, wthi, pmask, nmask, maskc);
    proj_k<<<240, 512, 0, stream>>>(qh, ph, nh, wthi, bias, maskc, qfrag, pfrag);
    interact_k<<<2304, 512, 0, stream>>>(qfrag, pfrag, out);
}

// Round 14
// 191.162 us; speedup vs baseline: 1.0308x; 1.0308x over previous
//
#include <hip/hip_runtime.h>

typedef __attribute__((ext_vector_type(4))) float f32x4;
typedef __attribute__((ext_vector_type(8))) short s16x8;
typedef __attribute__((ext_vector_type(4))) short s16x4;
typedef __bf16 bf16x4 __attribute__((ext_vector_type(4)));

#define B_   96
#define NQ   35
#define LP   180
#define H_   768
#define D_   128
#define NEGF (-1e30f)

#define NROWS 37920
#define QROWS 3360
#define PROWS 17280

__device__ __forceinline__ unsigned short f2bf(float f) {
    return __builtin_bit_cast(unsigned short, (__bf16)f);
}

__device__ __forceinline__ s16x8 pack_bf16(f32x4 v0, f32x4 v1) {
    bf16x4 h0 = __builtin_convertvector(v0, bf16x4);
    bf16x4 h1 = __builtin_convertvector(v1, bf16x4);
    s16x4 a = __builtin_bit_cast(s16x4, h0), b = __builtin_bit_cast(s16x4, h1);
    return __builtin_shufflevector(a, b, 0, 1, 2, 3, 4, 5, 6, 7);
}

// async global->LDS, 16 B per lane; lds dest must be wave-uniform (HW adds lane*16)
__device__ __forceinline__ void glds16(const void* g, void* l) {
    __builtin_amdgcn_global_load_lds(
        (const __attribute__((address_space(1))) unsigned int*)g,
        (__attribute__((address_space(3))) unsigned int*)l,
        16, 0, 0);
}

#define WAITV(N) do {                                                 \
    asm volatile("s_waitcnt vmcnt(" #N ")" ::: "memory");             \
    __builtin_amdgcn_sched_barrier(0);                                \
} while (0)

#define BAR() do {                                                    \
    __builtin_amdgcn_sched_barrier(0);                                \
    __builtin_amdgcn_s_barrier();                                     \
} while (0)

// ---------------- prep: wt_build (blocks 0-47) + mask canon w/ local detect (48-182) ----
__global__ __launch_bounds__(256) void prep_k(
    const float* __restrict__ W, unsigned short* __restrict__ wthi,
    const void* __restrict__ pm, const void* __restrict__ nm,
    unsigned char* __restrict__ maskc) {
    __shared__ unsigned int rr[256];
    int b = blockIdx.x, t = threadIdx.x;
    if (b < 48) {
        int tid = b * 256 + t;
        int nt = tid / (24 * 64);
        int r = tid - nt * 24 * 64;
        int ks = r / 64, lane = r - ks * 64;
        int m = lane & 15, quad = lane >> 4;
        unsigned short* o = wthi + (size_t)tid * 8;
#pragma unroll
        for (int j = 0; j < 8; j++) {
            int k = ks * 32 + quad * 8 + j;
            o[j] = f2bf(W[(size_t)k * D_ + nt * 16 + m]);
        }
    } else {
        const unsigned int* pw = (const unsigned int*)pm;
        unsigned int f1 = 0, f3 = 0, f4 = 0;
        for (int w = t; w < 4320; w += 256) {
            unsigned int v = pw[w];
            f1 |= v & 0x0000ff00u;                 // byte %4==1 -> 1-byte layout
            f3 |= v & 0xff000000u;                 // byte %4==3 -> float32
            if (w & 1) f4 |= v & 0x000000ffu;      // byte %8==4 -> int32
        }
        rr[t] = f1; __syncthreads();
        for (int s2 = 128; s2; s2 >>= 1) { if (t < s2) rr[t] |= rr[t + s2]; __syncthreads(); }
        unsigned int c1 = rr[0]; __syncthreads();
        rr[t] = f3; __syncthreads();
        for (int s2 = 128; s2; s2 >>= 1) { if (t < s2) rr[t] |= rr[t + s2]; __syncthreads(); }
        unsigned int c3 = rr[0]; __syncthreads();
        rr[t] = f4; __syncthreads();
        for (int s2 = 128; s2; s2 >>= 1) { if (t < s2) rr[t] |= rr[t + s2]; __syncthreads(); }
        unsigned int c4 = rr[0];
        int i = (b - 48) * 256 + t;                // < 34560 exactly (135 blocks)
        const void* src = (i < B_ * LP) ? pm : nm;
        int j = (i < B_ * LP) ? i : i - B_ * LP;
        bool bit;
        if (c1 > 0)       bit = ((const unsigned char*)src)[j] != 0;
        else if (c3 > 0)  bit = ((const float*)src)[j] != 0.0f;
        else if (c4 > 0)  bit = ((const int*)src)[j] != 0;
        else              bit = ((const long long*)src)[j] != 0;
        maskc[i] = bit ? 1 : 0;
    }
}

// ---------------- proj v11: v10 + 3-buffer glds ring w/ counted vmcnt (depth-2) ---------
// R13: v10 (1 block/CU) has ZERO inter-block TLP and __syncthreads drains vmcnt each
// step -> stage depth 1; per step the CU must land 48 KB (~1.8 us serial floor at the
// observed ~2.3 TB/s) hidden only by ~0.6 us of compute. v11 applies the v9-audited
// counted-vmcnt pattern to THIS structure: 3 x 48 KB LDS ring (144 KB <= 160), G(s+1)
// and G(s+2) in flight during compute(s) (96 KB outstanding/CU). Per-wave ledger
// (6 glds/stage): prologue G0,G1=12; steady WAITV(6) retires exactly G(s) BEFORE the
// raw s_barrier (each wave drains its own G(s) -> after barrier all waves' G(s) data
// is in LDS); stage(s+2) post-barrier rewrites slot (s-1)%3, which every wave finished
// reading before this barrier. Tail: s=11 WAITV(0). Same data, same compute order as
// v10 -> absmax unchanged. q-path: identical schedule with 3 glds/stage, 24 KB bufs.
__global__ __launch_bounds__(512, 1) void proj_k(
    const float* __restrict__ qh, const float* __restrict__ ph, const float* __restrict__ nh,
    const unsigned short* __restrict__ wthi, const float* __restrict__ bias,
    const unsigned char* __restrict__ maskc,
    unsigned short* __restrict__ qfrag, unsigned short* __restrict__ pfrag) {
    __shared__ float sb[36864];                      // 144 KB: 3-ring staging / xb reuse
    int b = blockIdx.x, t = threadIdx.x;
    int wave = t >> 6, lane = t & 63;
    int m = lane & 15, quad = lane >> 4;
    unsigned short* xb = (unsigned short*)sb;        // post-loop transpose buffer

#define PSTAGE(S) do {                                                \
    float* d0 = sb + ((S) % 3) * 12288 + wave * 1536;                 \
    _Pragma("unroll")                                                 \
    for (int g = 0; g < 6; g++) glds16(gp[g] + (S) * 64, d0 + g * 256); \
} while (0)

#define QSTAGE(S) do {                                                \
    float* d0 = sb + ((S) % 3) * 6144 + wave * 768;                   \
    _Pragma("unroll")                                                 \
    for (int g = 0; g < 3; g++) glds16(gp[g] + (S) * 64, d0 + g * 256); \
} while (0)

    if (b < 192) {
        const float* src = (b < 96) ? ph + (size_t)b * LP * H_
                                    : nh + (size_t)(b - 96) * LP * H_;
        const float* gp[6];
#pragma unroll
        for (int g = 0; g < 6; g++) {
            int rl = wave * 24 + g * 4 + (lane >> 4);
            int rc = rl < LP ? rl : LP - 1;
            gp[g] = src + (size_t)rc * H_ + (((lane & 15) ^ (2 * (rl & 7))) << 2);
        }

        f32x4 acc[12];
#pragma unroll
        for (int mt = 0; mt < 12; mt++) acc[mt] = (f32x4){0.f, 0.f, 0.f, 0.f};

        PSTAGE(0);                                   // ledger: G0(6)
        PSTAGE(1);                                   // + G1(6) = 12

        for (int s = 0; s < 12; s++) {
            if (s < 11) WAITV(6); else WAITV(0);     // retire G(s); keep G(s+1) in flight
            BAR();                                   // all waves' G(s) landed; buf s safe
            if (s < 10) PSTAGE(s + 2);               // rewrite slot (s-1)%3 (read done)
            const float* bb = sb + (s % 3) * 12288;
#pragma unroll
            for (int ksg = 0; ksg < 2; ksg++) {
                s16x8 bf = *(const s16x8*)(wthi +
                           ((size_t)(wave * 24 + s * 2 + ksg) * 64 + lane) * 8);
                int kc = ksg * 8 + quad * 2;
#pragma unroll
                for (int mt = 0; mt < 12; mt++) {
                    int row = mt * 16 + m;
                    const float* fb = bb + row * 64 + ((kc ^ (2 * (row & 7))) << 2);
                    f32x4 lo = *(const f32x4*)fb, hi = *(const f32x4*)(fb + 4);
                    acc[mt] = __builtin_amdgcn_mfma_f32_16x16x32_bf16(
                        pack_bf16(lo, hi), bf, acc[mt], 0, 0, 0);
                }
            }
        }

        float bv = bias[wave * 16 + m];
        float s2 = 0.f;
#pragma unroll
        for (int mt = 0; mt < 12; mt++)
#pragma unroll
            for (int r = 0; r < 4; r++) {
                int prow = mt * 16 + quad * 4 + r;
                float v = acc[mt][r] + bv;
                acc[mt][r] = v;
                if (prow < LP) s2 += v * v;
            }
        s2 += __shfl_xor(s2, 16); s2 += __shfl_xor(s2, 32);
        float sc = rsqrtf(fmaxf(s2, 1e-24f));
        __syncthreads();                             // staging dead; reuse as xb
#pragma unroll
        for (int mt = 0; mt < 12; mt++)
#pragma unroll
            for (int r = 0; r < 4; r++) {
                int prow = mt * 16 + quad * 4 + r;
                if (prow < LP) xb[prow * 136 + wave * 16 + m] = f2bf(acc[mt][r] * sc);
            }
        __syncthreads();
        const unsigned char* mk = maskc + b * LP;
        unsigned short* pdst = pfrag + (size_t)b * 24576;
#pragma unroll
        for (int i = 0; i < 6; i++) {
            int ch = t + i * 512;
            int ln = ch & 63;
            int l = ((ch >> 8) << 4) + (ln & 15);
            int lsrc = (l < LP && mk[l]) ? l : 0;
            int d0 = ((ch >> 6) & 3) * 32 + (ln >> 4) * 8;
            *(s16x8*)&pdst[(size_t)ch * 8] = *(const s16x8*)&xb[lsrc * 136 + d0];
        }
    } else {
        int qp = b - 192;                            // [0,48)
        const float* src = qh + (size_t)qp * 70 * H_;
        const float* gp[3];
#pragma unroll
        for (int g = 0; g < 3; g++) {
            int rl = wave * 12 + g * 4 + (lane >> 4);
            int rc = rl < 70 ? rl : 69;
            gp[g] = src + (size_t)rc * H_ + (((lane & 15) ^ (2 * (rl & 7))) << 2);
        }

        f32x4 acc[5];
#pragma unroll
        for (int mt = 0; mt < 5; mt++) acc[mt] = (f32x4){0.f, 0.f, 0.f, 0.f};

        QSTAGE(0);                                   // G0(3)
        QSTAGE(1);                                   // + G1(3) = 6

        for (int s = 0; s < 12; s++) {
            if (s < 11) WAITV(3); else WAITV(0);
            BAR();
            if (s < 10) QSTAGE(s + 2);
            const float* bb = sb + (s % 3) * 6144;
#pragma unroll
            for (int ksg = 0; ksg < 2; ksg++) {
                s16x8 bf = *(const s16x8*)(wthi +
                           ((size_t)(wave * 24 + s * 2 + ksg) * 64 + lane) * 8);
                int kc = ksg * 8 + quad * 2;
#pragma unroll
                for (int mt = 0; mt < 5; mt++) {
                    int row = mt * 16 + m;
                    const float* fb = bb + row * 64 + ((kc ^ (2 * (row & 7))) << 2);
                    f32x4 lo = *(const f32x4*)fb, hi = *(const f32x4*)(fb + 4);
                    acc[mt] = __builtin_amdgcn_mfma_f32_16x16x32_bf16(
                        pack_bf16(lo, hi), bf, acc[mt], 0, 0, 0);
                }
            }
        }

        float bv = bias[wave * 16 + m];
        float s0 = 0.f, s1 = 0.f;
#pragma unroll
        for (int mt = 0; mt < 5; mt++)
#pragma unroll
            for (int r = 0; r < 4; r++) {
                int prow = mt * 16 + quad * 4 + r;
                float v = acc[mt][r] + bv;
                acc[mt][r] = v;
                if (prow < 35) s0 += v * v;
                else if (prow < 70) s1 += v * v;
            }
        s0 += __shfl_xor(s0, 16); s0 += __shfl_xor(s0, 32);
        s1 += __shfl_xor(s1, 16); s1 += __shfl_xor(s1, 32);
        float sc0 = rsqrtf(fmaxf(s0, 1e-24f));
        float sc1 = rsqrtf(fmaxf(s1, 1e-24f));
        __syncthreads();
#pragma unroll
        for (int mt = 0; mt < 5; mt++)
#pragma unroll
            for (int r = 0; r < 4; r++) {
                int prow = mt * 16 + quad * 4 + r;
                if (prow < 70)
                    xb[prow * 136 + wave * 16 + m] =
                        f2bf(acc[mt][r] * (prow < 35 ? sc0 : sc1));
            }
        __syncthreads();
        unsigned short* qdst = qfrag + (size_t)qp * 10240;
#pragma unroll
        for (int i = 0; i < 3; i++) {
            int ch = t + i * 512;
            if (ch < 1280) {
                int ln = ch & 63;
                int prow = ((ch >> 8) << 4) + (ln & 15);
                int d0 = ((ch >> 6) & 3) * 32 + (ln >> 4) * 8;
                s16x8 v = (s16x8){0, 0, 0, 0, 0, 0, 0, 0};
                if (prow < 70) v = *(const s16x8*)&xb[prow * 136 + d0];
                *(s16x8*)&qdst[(size_t)ch * 8] = v;
            }
        }
    }
#undef PSTAGE
#undef QSTAGE
}

// ---------------- interact v5 (REVERTED from R12 -- best measured: ~35 us) --------------
// R13 verdict: v6 (single-pass, 2304 blocks) regressed to ~44 us -- per-block stage
// latency + re-staging outweighed the removed pass serialization. v5 (768 blocks,
// p staged once, 3 passes, wave-split halves) is the session-best interact. Verbatim.
__global__ __launch_bounds__(512, 1) void interact_k(
    const unsigned short* __restrict__ qfrag, const unsigned short* __restrict__ pfrag,
    float* __restrict__ out) {
    __shared__ unsigned short plds[24576];           // 48 KB p-tile, shared by all 8 waves
    __shared__ float comb[2][4][2];                  // [half][wq][s0/s1]
    int wave = threadIdx.x >> 6, lane = threadIdx.x & 63;
    int b = blockIdx.x;                              // 768 blocks
    int xcd = b & 7, i = b >> 3;                     // i in [0,96)
    int c = xcd * 24 + (i % 24);                     // [0,192)
    int qgg = i / 24;                                // [0,4)
    int side = c / 96, pb = c - side * 96;
    int wq = wave & 3, half = wave >> 2;
    int m = lane & 15, quad = lane >> 4;

    const unsigned short* pbase = pfrag + (size_t)c * 24576;

    // stage p-tile: waves 0-3 take nt {w, w+8}; waves 4-7 take nt {w}
#pragma unroll
    for (int g = 0; g < 2; g++) {
        int nt = wave + g * 8;
        if (nt < 12) {
#pragma unroll
            for (int ks = 0; ks < 4; ks++)
                glds16(pbase + ((size_t)(nt * 4 + ks) * 64 + lane) * 8,
                       &plds[(size_t)(nt * 4 + ks) * 512]);
        }
    }
    __syncthreads();                                 // drain staging; plds read-only after

    const f32x4 zero4 = (f32x4){0.f, 0.f, 0.f, 0.f};

#pragma unroll 1
    for (int pass = 0; pass < 3; pass++) {
        int qp = (qgg * 3 + pass) * 4 + wq;          // [0,48)
        const unsigned short* qbase = qfrag + (size_t)qp * 10240;
        float s0 = 0.f, s1 = 0.f;

        if (half == 0) {
            // ---------- waves 0-3: mts 0..2 (live ~95 VGPR) ----------
            s16x8 a[3][4];
#pragma unroll
            for (int mt = 0; mt < 3; mt++)
#pragma unroll
                for (int ks = 0; ks < 4; ks++)
                    a[mt][ks] = *(const s16x8*)(qbase +
                                ((size_t)(mt * 4 + ks) * 64 + lane) * 8);
            float rmax[3][4];
#pragma unroll
            for (int mt = 0; mt < 3; mt++)
#pragma unroll
                for (int rr = 0; rr < 4; rr++) rmax[mt][rr] = NEGF;

            for (int nt = 0; nt < 12; nt++) {
                s16x8 bfr[4];
#pragma unroll
                for (int ks = 0; ks < 4; ks++)
                    bfr[ks] = *(const s16x8*)&plds[((size_t)(nt * 4 + ks) * 64 + lane) * 8];
                __builtin_amdgcn_s_setprio(1);
#pragma unroll
                for (int mt = 0; mt < 3; mt++) {
                    f32x4 acc = __builtin_amdgcn_mfma_f32_16x16x32_bf16(a[mt][0], bfr[0], zero4, 0, 0, 0);
                    acc = __builtin_amdgcn_mfma_f32_16x16x32_bf16(a[mt][1], bfr[1], acc, 0, 0, 0);
                    acc = __builtin_amdgcn_mfma_f32_16x16x32_bf16(a[mt][2], bfr[2], acc, 0, 0, 0);
                    acc = __builtin_amdgcn_mfma_f32_16x16x32_bf16(a[mt][3], bfr[3], acc, 0, 0, 0);
#pragma unroll
                    for (int rr = 0; rr < 4; rr++)
                        rmax[mt][rr] = fmaxf(rmax[mt][rr], acc[rr]);
                }
                __builtin_amdgcn_s_setprio(0);
            }
#pragma unroll
            for (int mt = 0; mt < 3; mt++)
#pragma unroll
                for (int rr = 0; rr < 4; rr++) {
                    float v = rmax[mt][rr];
                    v = fmaxf(v, __shfl_xor(v, 1));
                    v = fmaxf(v, __shfl_xor(v, 2));
                    v = fmaxf(v, __shfl_xor(v, 4));
                    v = fmaxf(v, __shfl_xor(v, 8));
                    int prow = mt * 16 + quad * 4 + rr;
                    if (prow < 35) s0 += v;
                    else if (prow < 70) s1 += v;
                }
        } else {
            // ---------- waves 4-7: mts 3..4 (live ~75 VGPR) ----------
            s16x8 a[2][4];
#pragma unroll
            for (int mt = 0; mt < 2; mt++)
#pragma unroll
                for (int ks = 0; ks < 4; ks++)
                    a[mt][ks] = *(const s16x8*)(qbase +
                                ((size_t)((mt + 3) * 4 + ks) * 64 + lane) * 8);
            float rmax[2][4];
#pragma unroll
            for (int mt = 0; mt < 2; mt++)
#pragma unroll
                for (int rr = 0; rr < 4; rr++) rmax[mt][rr] = NEGF;

            for (int nt = 0; nt < 12; nt++) {
                s16x8 bfr[4];
#pragma unroll
                for (int ks = 0; ks < 4; ks++)
                    bfr[ks] = *(const s16x8*)&plds[((size_t)(nt * 4 + ks) * 64 + lane) * 8];
                __builtin_amdgcn_s_setprio(1);
#pragma unroll
                for (int mt = 0; mt < 2; mt++) {
                    f32x4 acc = __builtin_amdgcn_mfma_f32_16x16x32_bf16(a[mt][0], bfr[0], zero4, 0, 0, 0);
                    acc = __builtin_amdgcn_mfma_f32_16x16x32_bf16(a[mt][1], bfr[1], acc, 0, 0, 0);
                    acc = __builtin_amdgcn_mfma_f32_16x16x32_bf16(a[mt][2], bfr[2], acc, 0, 0, 0);
                    acc = __builtin_amdgcn_mfma_f32_16x16x32_bf16(a[mt][3], bfr[3], acc, 0, 0, 0);
#pragma unroll
                    for (int rr = 0; rr < 4; rr++)
                        rmax[mt][rr] = fmaxf(rmax[mt][rr], acc[rr]);
                }
                __builtin_amdgcn_s_setprio(0);
            }
#pragma unroll
            for (int mt = 0; mt < 2; mt++)
#pragma unroll
                for (int rr = 0; rr < 4; rr++) {
                    float v = rmax[mt][rr];
                    v = fmaxf(v, __shfl_xor(v, 1));
                    v = fmaxf(v, __shfl_xor(v, 2));
                    v = fmaxf(v, __shfl_xor(v, 4));
                    v = fmaxf(v, __shfl_xor(v, 8));
                    int prow = (mt + 3) * 16 + quad * 4 + rr;
                    if (prow < 35) s0 += v;
                    else if (prow < 70) s1 += v;
                }
        }

        s0 += __shfl_xor(s0, 16); s0 += __shfl_xor(s0, 32);
        s1 += __shfl_xor(s1, 16); s1 += __shfl_xor(s1, 32);
        if (lane == 0) { comb[half][wq][0] = s0; comb[half][wq][1] = s1; }
        __syncthreads();                             // partials visible
        if (half == 0 && lane == 0) {
            int qb0 = qp * 2, qb1 = qp * 2 + 1;
            out[(size_t)qb0 * (2 * B_) + side * B_ + pb] = s0 + comb[1][wq][0];
            out[(size_t)qb1 * (2 * B_) + side * B_ + pb] = s1 + comb[1][wq][1];
        }
        __syncthreads();                             // protect comb before next pass
    }
}

// ---------------- launch ----------------
extern "C" void kernel_launch(void* const* d_in, const int* in_sizes, int n_in,
                              void* d_out, int out_size, void* d_ws, size_t ws_size,
                              hipStream_t stream) {
    const float* qh   = (const float*)d_in[0];
    const float* ph   = (const float*)d_in[1];
    const float* nh   = (const float*)d_in[2];
    const float* W    = (const float*)d_in[3];
    const float* bias = (const float*)d_in[4];
    const void* pmask = d_in[5];
    const void* nmask = d_in[6];
    float* out = (float*)d_out;
    char* ws = (char*)d_ws;

    constexpr size_t WTHI_OFF  = 256;                        // 196608 B
    constexpr size_t MASKC_OFF = WTHI_OFF + 196608;          // 34560 B
    constexpr size_t QFRAG_OFF = MASKC_OFF + 34560;          // 983040 B
    constexpr size_t PFRAG_OFF = QFRAG_OFF + 983040;         // 9437184 B

    unsigned short* wthi   = (unsigned short*)(ws + WTHI_OFF);
    unsigned char* maskc   = (unsigned char*)(ws + MASKC_OFF);
    unsigned short* qfrag  = (unsigned short*)(ws + QFRAG_OFF);
    unsigned short* pfrag  = (unsigned short*)(ws + PFRAG_OFF);

    prep_k<<<183, 256, 0, stream>>>(W, wthi, pmask, nmask, maskc);
    proj_k<<<240, 512, 0, stream>>>(qh, ph, nh, wthi, bias, maskc, qfrag, pfrag);
    interact_k<<<768, 512, 0, stream>>>(qfrag, pfrag, out);
}

// Round 15
// 187.737 us; speedup vs baseline: 1.0496x; 1.0182x over previous
//
#include <hip/hip_runtime.h>

typedef __attribute__((ext_vector_type(4))) float f32x4;
typedef __attribute__((ext_vector_type(8))) short s16x8;
typedef __attribute__((ext_vector_type(4))) short s16x4;
typedef __bf16 bf16x4 __attribute__((ext_vector_type(4)));

#define B_   96
#define NQ   35
#define LP   180
#define H_   768
#define D_   128
#define NEGF (-1e30f)

#define NROWS 37920
#define QROWS 3360
#define PROWS 17280

__device__ __forceinline__ unsigned short f2bf(float f) {
    return __builtin_bit_cast(unsigned short, (__bf16)f);
}

__device__ __forceinline__ s16x8 pack_bf16(f32x4 v0, f32x4 v1) {
    bf16x4 h0 = __builtin_convertvector(v0, bf16x4);
    bf16x4 h1 = __builtin_convertvector(v1, bf16x4);
    s16x4 a = __builtin_bit_cast(s16x4, h0), b = __builtin_bit_cast(s16x4, h1);
    return __builtin_shufflevector(a, b, 0, 1, 2, 3, 4, 5, 6, 7);
}

// async global->LDS, 16 B per lane; lds dest must be wave-uniform (HW adds lane*16)
__device__ __forceinline__ void glds16(const void* g, void* l) {
    __builtin_amdgcn_global_load_lds(
        (const __attribute__((address_space(1))) unsigned int*)g,
        (__attribute__((address_space(3))) unsigned int*)l,
        16, 0, 0);
}

// ---------------- prep: wt_build (blocks 0-47) + mask canon w/ local detect (48-182) ----
__global__ __launch_bounds__(256) void prep_k(
    const float* __restrict__ W, unsigned short* __restrict__ wthi,
    const void* __restrict__ pm, const void* __restrict__ nm,
    unsigned char* __restrict__ maskc) {
    __shared__ unsigned int rr[256];
    int b = blockIdx.x, t = threadIdx.x;
    if (b < 48) {
        int tid = b * 256 + t;
        int nt = tid / (24 * 64);
        int r = tid - nt * 24 * 64;
        int ks = r / 64, lane = r - ks * 64;
        int m = lane & 15, quad = lane >> 4;
        unsigned short* o = wthi + (size_t)tid * 8;
#pragma unroll
        for (int j = 0; j < 8; j++) {
            int k = ks * 32 + quad * 8 + j;
            o[j] = f2bf(W[(size_t)k * D_ + nt * 16 + m]);
        }
    } else {
        const unsigned int* pw = (const unsigned int*)pm;
        unsigned int f1 = 0, f3 = 0, f4 = 0;
        for (int w = t; w < 4320; w += 256) {
            unsigned int v = pw[w];
            f1 |= v & 0x0000ff00u;                 // byte %4==1 -> 1-byte layout
            f3 |= v & 0xff000000u;                 // byte %4==3 -> float32
            if (w & 1) f4 |= v & 0x000000ffu;      // byte %8==4 -> int32
        }
        rr[t] = f1; __syncthreads();
        for (int s2 = 128; s2; s2 >>= 1) { if (t < s2) rr[t] |= rr[t + s2]; __syncthreads(); }
        unsigned int c1 = rr[0]; __syncthreads();
        rr[t] = f3; __syncthreads();
        for (int s2 = 128; s2; s2 >>= 1) { if (t < s2) rr[t] |= rr[t + s2]; __syncthreads(); }
        unsigned int c3 = rr[0]; __syncthreads();
        rr[t] = f4; __syncthreads();
        for (int s2 = 128; s2; s2 >>= 1) { if (t < s2) rr[t] |= rr[t + s2]; __syncthreads(); }
        unsigned int c4 = rr[0];
        int i = (b - 48) * 256 + t;                // < 34560 exactly (135 blocks)
        const void* src = (i < B_ * LP) ? pm : nm;
        int j = (i < B_ * LP) ? i : i - B_ * LP;
        bool bit;
        if (c1 > 0)       bit = ((const unsigned char*)src)[j] != 0;
        else if (c3 > 0)  bit = ((const float*)src)[j] != 0.0f;
        else if (c4 > 0)  bit = ((const int*)src)[j] != 0;
        else              bit = ((const long long*)src)[j] != 0;
        maskc[i] = bit ? 1 : 0;
    }
}

// ---------------- proj v12: 4m x 2n wave ownership + full-bank swizzle ------------------
// R14 diagnosis (first quantitative fit in 8 rounds): v10 is LDS-READ-BW bound.
//   (a) waves owned COLUMNS -> all 8 waves read the ENTIRE 48 KB A-step tile:
//       8x48 read + 48 write = 432 KB/step / 112 B/clk/CU ~= 3.9k clk of the ~10k step;
//   (b) read chunk = kc ^ 2*(row&7): both terms EVEN -> only even 16B chunks -> 16 of
//       32 banks used -> 2x the b128 bank floor (SQ_LDS_BANK_CONFLICT 3.95M/dispatch).
// v12: waves = 4 m-groups x 2 n-groups (3 mt-rows x 64 cols each) -> A-rows read by
// only 2 waves (432 -> 144 KB/step); source swizzle widened to cg = (lane&15)^(row&15)
// (staging AND read changed together, rule #21) -> chunks cover all 32 banks.
// B now 8 KB/wave-step from L2-hot wthi (184 MB aggregate ~ 5 us). Per-output MFMA
// accumulation order unchanged -> bit-identical acc; ssq becomes cross-wave LDS
// reduction (f32 noise only). Staging (glds, 2-buf, __syncthreads) verbatim from v10.
__global__ __launch_bounds__(512, 1) void proj_k(
    const float* __restrict__ qh, const float* __restrict__ ph, const float* __restrict__ nh,
    const unsigned short* __restrict__ wthi, const float* __restrict__ bias,
    const unsigned char* __restrict__ maskc,
    unsigned short* __restrict__ qfrag, unsigned short* __restrict__ pfrag) {
    __shared__ float sb[24576];                      // 96 KB: 2 x 192 x 64 f32 staging
    int b = blockIdx.x, t = threadIdx.x;
    int wave = t >> 6, lane = t & 63;
    int m = lane & 15, quad = lane >> 4;
    int mg = wave & 3, ng = wave >> 2;               // 4 m-groups x 2 n-groups
    unsigned short* xb = (unsigned short*)sb;        // post-loop transpose buffer
    float* ssql = sb + 23040;                        // cross-wave ssq partials (<=1024 f)

    if (b < 192) {
        // ================= passage block: 180 rows (12 mt), 128 cols =================
        const float* src = (b < 96) ? ph + (size_t)b * LP * H_
                                    : nh + (size_t)(b - 96) * LP * H_;
        const float* gp[6];
#pragma unroll
        for (int g = 0; g < 6; g++) {
            int rl = wave * 24 + g * 4 + (lane >> 4);
            int rc = rl < LP ? rl : LP - 1;
            gp[g] = src + (size_t)rc * H_ + (((lane & 15) ^ (rl & 15)) << 2);
        }

        f32x4 acc[3][4];                             // [mtl][ntl]
#pragma unroll
        for (int mtl = 0; mtl < 3; mtl++)
#pragma unroll
            for (int ntl = 0; ntl < 4; ntl++) acc[mtl][ntl] = (f32x4){0.f, 0.f, 0.f, 0.f};

        {
            float* d0 = sb + wave * 1536;
#pragma unroll
            for (int g = 0; g < 6; g++) glds16(gp[g], d0 + g * 256);
        }
        __syncthreads();

        for (int s = 0; s < 12; s++) {
            if (s < 11) {
                float* d0 = sb + ((s + 1) & 1) * 12288 + wave * 1536;
#pragma unroll
                for (int g = 0; g < 6; g++) glds16(gp[g] + (s + 1) * 64, d0 + g * 256);
            }
            const float* bb = sb + (s & 1) * 12288;
#pragma unroll
            for (int ksg = 0; ksg < 2; ksg++) {
                s16x8 bf[4];
#pragma unroll
                for (int ntl = 0; ntl < 4; ntl++)
                    bf[ntl] = *(const s16x8*)(wthi +
                              ((size_t)((ng * 4 + ntl) * 24 + s * 2 + ksg) * 64 + lane) * 8);
                int kc = ksg * 8 + quad * 2;
#pragma unroll
                for (int mtl = 0; mtl < 3; mtl++) {
                    int row = (mtl * 4 + mg) * 16 + m;
                    int sw = row & 15;
                    const float* rbase = bb + row * 64;
                    f32x4 lo = *(const f32x4*)(rbase + ((kc ^ sw) << 2));
                    f32x4 hi = *(const f32x4*)(rbase + (((kc + 1) ^ sw) << 2));
                    s16x8 af = pack_bf16(lo, hi);
#pragma unroll
                    for (int ntl = 0; ntl < 4; ntl++)
                        acc[mtl][ntl] = __builtin_amdgcn_mfma_f32_16x16x32_bf16(
                            af, bf[ntl], acc[mtl][ntl], 0, 0, 0);
                }
            }
            __syncthreads();
        }

        // epilogue: bias + cross-wave ssq + scale + LDS transpose + masked frag scatter
        float bvv[4], part[4];
#pragma unroll
        for (int ntl = 0; ntl < 4; ntl++) {
            bvv[ntl] = bias[ng * 64 + ntl * 16 + m];
            part[ntl] = 0.f;
        }
#pragma unroll
        for (int mtl = 0; mtl < 3; mtl++)
#pragma unroll
            for (int ntl = 0; ntl < 4; ntl++)
#pragma unroll
                for (int r = 0; r < 4; r++) {
                    int prow = (mtl * 4 + mg) * 16 + quad * 4 + r;
                    float v = acc[mtl][ntl][r] + bvv[ntl];
                    acc[mtl][ntl][r] = v;
                    if (prow < LP) part[ntl] += v * v;
                }
#pragma unroll
        for (int ntl = 0; ntl < 4; ntl++) {
            part[ntl] += __shfl_xor(part[ntl], 16);
            part[ntl] += __shfl_xor(part[ntl], 32);
        }
        if (quad == 0) {
#pragma unroll
            for (int ntl = 0; ntl < 4; ntl++)
                ssql[mg * 128 + ng * 64 + ntl * 16 + m] = part[ntl];
        }
        __syncthreads();
        float sc[4];
#pragma unroll
        for (int ntl = 0; ntl < 4; ntl++) {
            int col = ng * 64 + ntl * 16 + m;
            float s2 = ssql[col] + ssql[128 + col] + ssql[256 + col] + ssql[384 + col];
            sc[ntl] = rsqrtf(fmaxf(s2, 1e-24f));
        }
        __syncthreads();                             // ssql read done; sb free for xb
#pragma unroll
        for (int mtl = 0; mtl < 3; mtl++)
#pragma unroll
            for (int ntl = 0; ntl < 4; ntl++)
#pragma unroll
                for (int r = 0; r < 4; r++) {
                    int prow = (mtl * 4 + mg) * 16 + quad * 4 + r;
                    if (prow < LP)
                        xb[prow * 136 + ng * 64 + ntl * 16 + m] =
                            f2bf(acc[mtl][ntl][r] * sc[ntl]);
                }
        __syncthreads();
        const unsigned char* mk = maskc + b * LP;
        unsigned short* pdst = pfrag + (size_t)b * 24576;
#pragma unroll
        for (int i = 0; i < 6; i++) {                // 3072 chunks = 6 x 512
            int ch = t + i * 512;
            int ln = ch & 63;
            int l = ((ch >> 8) << 4) + (ln & 15);
            int lsrc = (l < LP && mk[l]) ? l : 0;
            int d0 = ((ch >> 6) & 3) * 32 + (ln >> 4) * 8;
            *(s16x8*)&pdst[(size_t)ch * 8] = *(const s16x8*)&xb[lsrc * 136 + d0];
        }
    } else {
        // ================= q block: 2 passages = 70 rows (5 mt: mi = mtl*4+mg) =========
        int qp = b - 192;                            // [0,48)
        const float* src = qh + (size_t)qp * 70 * H_;
        const float* gp[3];
#pragma unroll
        for (int g = 0; g < 3; g++) {
            int rl = wave * 12 + g * 4 + (lane >> 4);
            int rc = rl < 70 ? rl : 69;
            gp[g] = src + (size_t)rc * H_ + (((lane & 15) ^ (rl & 15)) << 2);
        }

        f32x4 acc[2][4];                             // [mtl][ntl]; mtl 1 only for mg==0
#pragma unroll
        for (int mtl = 0; mtl < 2; mtl++)
#pragma unroll
            for (int ntl = 0; ntl < 4; ntl++) acc[mtl][ntl] = (f32x4){0.f, 0.f, 0.f, 0.f};

        {
            float* d0 = sb + wave * 768;
#pragma unroll
            for (int g = 0; g < 3; g++) glds16(gp[g], d0 + g * 256);
        }
        __syncthreads();

        for (int s = 0; s < 12; s++) {
            if (s < 11) {
                float* d0 = sb + ((s + 1) & 1) * 6144 + wave * 768;
#pragma unroll
                for (int g = 0; g < 3; g++) glds16(gp[g] + (s + 1) * 64, d0 + g * 256);
            }
            const float* bb = sb + (s & 1) * 6144;
#pragma unroll
            for (int ksg = 0; ksg < 2; ksg++) {
                s16x8 bf[4];
#pragma unroll
                for (int ntl = 0; ntl < 4; ntl++)
                    bf[ntl] = *(const s16x8*)(wthi +
                              ((size_t)((ng * 4 + ntl) * 24 + s * 2 + ksg) * 64 + lane) * 8);
                int kc = ksg * 8 + quad * 2;
#pragma unroll
                for (int mtl = 0; mtl < 2; mtl++) {
                    int mi = mtl * 4 + mg;
                    if (mi < 5) {
                        int row = mi * 16 + m;
                        int sw = row & 15;
                        const float* rbase = bb + row * 64;
                        f32x4 lo = *(const f32x4*)(rbase + ((kc ^ sw) << 2));
                        f32x4 hi = *(const f32x4*)(rbase + (((kc + 1) ^ sw) << 2));
                        s16x8 af = pack_bf16(lo, hi);
#pragma unroll
                        for (int ntl = 0; ntl < 4; ntl++)
                            acc[mtl][ntl] = __builtin_amdgcn_mfma_f32_16x16x32_bf16(
                                af, bf[ntl], acc[mtl][ntl], 0, 0, 0);
                    }
                }
            }
            __syncthreads();
        }

        // epilogue: bias + cross-wave split ssq (two sub-passages) + scale + transpose
        float bvv[4], p0[4], p1[4];
#pragma unroll
        for (int ntl = 0; ntl < 4; ntl++) {
            bvv[ntl] = bias[ng * 64 + ntl * 16 + m];
            p0[ntl] = 0.f; p1[ntl] = 0.f;
        }
#pragma unroll
        for (int mtl = 0; mtl < 2; mtl++) {
            int mi = mtl * 4 + mg;
            if (mi < 5) {
#pragma unroll
                for (int ntl = 0; ntl < 4; ntl++)
#pragma unroll
                    for (int r = 0; r < 4; r++) {
                        int prow = mi * 16 + quad * 4 + r;
                        float v = acc[mtl][ntl][r] + bvv[ntl];
                        acc[mtl][ntl][r] = v;
                        if (prow < 35) p0[ntl] += v * v;
                        else if (prow < 70) p1[ntl] += v * v;
                    }
            }
        }
#pragma unroll
        for (int ntl = 0; ntl < 4; ntl++) {
            p0[ntl] += __shfl_xor(p0[ntl], 16); p0[ntl] += __shfl_xor(p0[ntl], 32);
            p1[ntl] += __shfl_xor(p1[ntl], 16); p1[ntl] += __shfl_xor(p1[ntl], 32);
        }
        if (quad == 0) {
#pragma unroll
            for (int ntl = 0; ntl < 4; ntl++) {
                int col = ng * 64 + ntl * 16 + m;
                ssql[(mg * 128 + col) * 2 + 0] = p0[ntl];
                ssql[(mg * 128 + col) * 2 + 1] = p1[ntl];
            }
        }
        __syncthreads();
        float sc0[4], sc1[4];
#pragma unroll
        for (int ntl = 0; ntl < 4; ntl++) {
            int col = ng * 64 + ntl * 16 + m;
            float a0 = 0.f, a1 = 0.f;
#pragma unroll
            for (int g2 = 0; g2 < 4; g2++) {
                a0 += ssql[(g2 * 128 + col) * 2 + 0];
                a1 += ssql[(g2 * 128 + col) * 2 + 1];
            }
            sc0[ntl] = rsqrtf(fmaxf(a0, 1e-24f));
            sc1[ntl] = rsqrtf(fmaxf(a1, 1e-24f));
        }
        __syncthreads();                             // ssql read done; sb free for xb
#pragma unroll
        for (int mtl = 0; mtl < 2; mtl++) {
            int mi = mtl * 4 + mg;
            if (mi < 5) {
#pragma unroll
                for (int ntl = 0; ntl < 4; ntl++)
#pragma unroll
                    for (int r = 0; r < 4; r++) {
                        int prow = mi * 16 + quad * 4 + r;
                        if (prow < 70)
                            xb[prow * 136 + ng * 64 + ntl * 16 + m] =
                                f2bf(acc[mtl][ntl][r] * (prow < 35 ? sc0[ntl] : sc1[ntl]));
                    }
            }
        }
        __syncthreads();
        unsigned short* qdst = qfrag + (size_t)qp * 10240;
#pragma unroll
        for (int i = 0; i < 3; i++) {                // 1280 chunks = 2x512 + 256
            int ch = t + i * 512;
            if (ch < 1280) {
                int ln = ch & 63;
                int prow = ((ch >> 8) << 4) + (ln & 15);
                int d0 = ((ch >> 6) & 3) * 32 + (ln >> 4) * 8;
                s16x8 v = (s16x8){0, 0, 0, 0, 0, 0, 0, 0};
                if (prow < 70) v = *(const s16x8*)&xb[prow * 136 + d0];
                *(s16x8*)&qdst[(size_t)ch * 8] = v;
            }
        }
    }
}

// ---------------- interact v5 (R12-verified best: ~35 us) -- verbatim -------------------
__global__ __launch_bounds__(512, 1) void interact_k(
    const unsigned short* __restrict__ qfrag, const unsigned short* __restrict__ pfrag,
    float* __restrict__ out) {
    __shared__ unsigned short plds[24576];           // 48 KB p-tile, shared by all 8 waves
    __shared__ float comb[2][4][2];                  // [half][wq][s0/s1]
    int wave = threadIdx.x >> 6, lane = threadIdx.x & 63;
    int b = blockIdx.x;                              // 768 blocks
    int xcd = b & 7, i = b >> 3;                     // i in [0,96)
    int c = xcd * 24 + (i % 24);                     // [0,192)
    int qgg = i / 24;                                // [0,4)
    int side = c / 96, pb = c - side * 96;
    int wq = wave & 3, half = wave >> 2;
    int m = lane & 15, quad = lane >> 4;

    const unsigned short* pbase = pfrag + (size_t)c * 24576;

#pragma unroll
    for (int g = 0; g < 2; g++) {
        int nt = wave + g * 8;
        if (nt < 12) {
#pragma unroll
            for (int ks = 0; ks < 4; ks++)
                glds16(pbase + ((size_t)(nt * 4 + ks) * 64 + lane) * 8,
                       &plds[(size_t)(nt * 4 + ks) * 512]);
        }
    }
    __syncthreads();                                 // drain staging; plds read-only after

    const f32x4 zero4 = (f32x4){0.f, 0.f, 0.f, 0.f};

#pragma unroll 1
    for (int pass = 0; pass < 3; pass++) {
        int qp = (qgg * 3 + pass) * 4 + wq;          // [0,48)
        const unsigned short* qbase = qfrag + (size_t)qp * 10240;
        float s0 = 0.f, s1 = 0.f;

        if (half == 0) {
            s16x8 a[3][4];
#pragma unroll
            for (int mt = 0; mt < 3; mt++)
#pragma unroll
                for (int ks = 0; ks < 4; ks++)
                    a[mt][ks] = *(const s16x8*)(qbase +
                                ((size_t)(mt * 4 + ks) * 64 + lane) * 8);
            float rmax[3][4];
#pragma unroll
            for (int mt = 0; mt < 3; mt++)
#pragma unroll
                for (int rr = 0; rr < 4; rr++) rmax[mt][rr] = NEGF;

            for (int nt = 0; nt < 12; nt++) {
                s16x8 bfr[4];
#pragma unroll
                for (int ks = 0; ks < 4; ks++)
                    bfr[ks] = *(const s16x8*)&plds[((size_t)(nt * 4 + ks) * 64 + lane) * 8];
                __builtin_amdgcn_s_setprio(1);
#pragma unroll
                for (int mt = 0; mt < 3; mt++) {
                    f32x4 acc = __builtin_amdgcn_mfma_f32_16x16x32_bf16(a[mt][0], bfr[0], zero4, 0, 0, 0);
                    acc = __builtin_amdgcn_mfma_f32_16x16x32_bf16(a[mt][1], bfr[1], acc, 0, 0, 0);
                    acc = __builtin_amdgcn_mfma_f32_16x16x32_bf16(a[mt][2], bfr[2], acc, 0, 0, 0);
                    acc = __builtin_amdgcn_mfma_f32_16x16x32_bf16(a[mt][3], bfr[3], acc, 0, 0, 0);
#pragma unroll
                    for (int rr = 0; rr < 4; rr++)
                        rmax[mt][rr] = fmaxf(rmax[mt][rr], acc[rr]);
                }
                __builtin_amdgcn_s_setprio(0);
            }
#pragma unroll
            for (int mt = 0; mt < 3; mt++)
#pragma unroll
                for (int rr = 0; rr < 4; rr++) {
                    float v = rmax[mt][rr];
                    v = fmaxf(v, __shfl_xor(v, 1));
                    v = fmaxf(v, __shfl_xor(v, 2));
                    v = fmaxf(v, __shfl_xor(v, 4));
                    v = fmaxf(v, __shfl_xor(v, 8));
                    int prow = mt * 16 + quad * 4 + rr;
                    if (prow < 35) s0 += v;
                    else if (prow < 70) s1 += v;
                }
        } else {
            s16x8 a[2][4];
#pragma unroll
            for (int mt = 0; mt < 2; mt++)
#pragma unroll
                for (int ks = 0; ks < 4; ks++)
                    a[mt][ks] = *(const s16x8*)(qbase +
                                ((size_t)((mt + 3) * 4 + ks) * 64 + lane) * 8);
            float rmax[2][4];
#pragma unroll
            for (int mt = 0; mt < 2; mt++)
#pragma unroll
                for (int rr = 0; rr < 4; rr++) rmax[mt][rr] = NEGF;

            for (int nt = 0; nt < 12; nt++) {
                s16x8 bfr[4];
#pragma unroll
                for (int ks = 0; ks < 4; ks++)
                    bfr[ks] = *(const s16x8*)&plds[((size_t)(nt * 4 + ks) * 64 + lane) * 8];
                __builtin_amdgcn_s_setprio(1);
#pragma unroll
                for (int mt = 0; mt < 2; mt++) {
                    f32x4 acc = __builtin_amdgcn_mfma_f32_16x16x32_bf16(a[mt][0], bfr[0], zero4, 0, 0, 0);
                    acc = __builtin_amdgcn_mfma_f32_16x16x32_bf16(a[mt][1], bfr[1], acc, 0, 0, 0);
                    acc = __builtin_amdgcn_mfma_f32_16x16x32_bf16(a[mt][2], bfr[2], acc, 0, 0, 0);
                    acc = __builtin_amdgcn_mfma_f32_16x16x32_bf16(a[mt][3], bfr[3], acc, 0, 0, 0);
#pragma unroll
                    for (int rr = 0; rr < 4; rr++)
                        rmax[mt][rr] = fmaxf(rmax[mt][rr], acc[rr]);
                }
                __builtin_amdgcn_s_setprio(0);
            }
#pragma unroll
            for (int mt = 0; mt < 2; mt++)
#pragma unroll
                for (int rr = 0; rr < 4; rr++) {
                    float v = rmax[mt][rr];
                    v = fmaxf(v, __shfl_xor(v, 1));
                    v = fmaxf(v, __shfl_xor(v, 2));
                    v = fmaxf(v, __shfl_xor(v, 4));
                    v = fmaxf(v, __shfl_xor(v, 8));
                    int prow = (mt + 3) * 16 + quad * 4 + rr;
                    if (prow < 35) s0 += v;
                    else if (prow < 70) s1 += v;
                }
        }

        s0 += __shfl_xor(s0, 16); s0 += __shfl_xor(s0, 32);
        s1 += __shfl_xor(s1, 16); s1 += __shfl_xor(s1, 32);
        if (lane == 0) { comb[half][wq][0] = s0; comb[half][wq][1] = s1; }
        __syncthreads();                             // partials visible
        if (half == 0 && lane == 0) {
            int qb0 = qp * 2, qb1 = qp * 2 + 1;
            out[(size_t)qb0 * (2 * B_) + side * B_ + pb] = s0 + comb[1][wq][0];
            out[(size_t)qb1 * (2 * B_) + side * B_ + pb] = s1 + comb[1][wq][1];
        }
        __syncthreads();                             // protect comb before next pass
    }
}

// ---------------- launch ----------------
extern "C" void kernel_launch(void* const* d_in, const int* in_sizes, int n_in,
                              void* d_out, int out_size, void* d_ws, size_t ws_size,
                              hipStream_t stream) {
    const float* qh   = (const float*)d_in[0];
    const float* ph   = (const float*)d_in[1];
    const float* nh   = (const float*)d_in[2];
    const float* W    = (const float*)d_in[3];
    const float* bias = (const float*)d_in[4];
    const void* pmask = d_in[5];
    const void* nmask = d_in[6];
    float* out = (float*)d_out;
    char* ws = (char*)d_ws;

    constexpr size_t WTHI_OFF  = 256;                        // 196608 B
    constexpr size_t MASKC_OFF = WTHI_OFF + 196608;          // 34560 B
    constexpr size_t QFRAG_OFF = MASKC_OFF + 34560;          // 983040 B
    constexpr size_t PFRAG_OFF = QFRAG_OFF + 983040;         // 9437184 B

    unsigned short* wthi   = (unsigned short*)(ws + WTHI_OFF);
    unsigned char* maskc   = (unsigned char*)(ws + MASKC_OFF);
    unsigned short* qfrag  = (unsigned short*)(ws + QFRAG_OFF);
    unsigned short* pfrag  = (unsigned short*)(ws + PFRAG_OFF);

    prep_k<<<183, 256, 0, stream>>>(W, wthi, pmask, nmask, maskc);
    proj_k<<<240, 512, 0, stream>>>(qh, ph, nh, wthi, bias, maskc, qfrag, pfrag);
    interact_k<<<768, 512, 0, stream>>>(qfrag, pfrag, out);
}